// Round 3
// baseline (34.825 us; speedup 1.0000x reference)
//
#include <hip/hip_runtime.h>

#define NT 512
#define NBOX 4096
#define NPT 8        // NBOX / NT
#define MAXDET 100
#define KSEL 192     // top-K selection target (>= 100 + NMS-suppressed margin)
#define CAP 512      // candidate capacity

typedef unsigned long long u64;
typedef unsigned int u32;

__device__ __forceinline__ float iou_xyxy(float4 a, float4 c) {
  float aa = fmaxf(a.z - a.x, 0.f) * fmaxf(a.w - a.y, 0.f);
  float ca = fmaxf(c.z - c.x, 0.f) * fmaxf(c.w - c.y, 0.f);
  float w = fmaxf(fminf(a.z, c.z) - fmaxf(a.x, c.x), 0.f);
  float h = fmaxf(fminf(a.w, c.w) - fmaxf(a.y, c.y), 0.f);
  float inter = w * h;
  return inter / fmaxf(aa + ca - inter, 1e-9f);
}

// Barrier-free descending bitonic sort of S=R*64 u64 keys by ONE wave.
// Element i = r*64 + lane lives in v[r] of `lane`. Pads with 0 beyond C.
template <int R>
__device__ void wave_sort(u64* keys, int C, int lane) {
  u64 v[R];
#pragma unroll
  for (int r = 0; r < R; ++r) {
    int i = r * 64 + lane;
    v[r] = (i < C) ? keys[i] : 0ull;
  }
  const int S = R * 64;
  for (int k = 2; k <= S; k <<= 1) {
    for (int j = k >> 1; j > 0; j >>= 1) {
      if (j >= 64) {
        int jj = j >> 6;
#pragma unroll
        for (int r = 0; r < R; ++r)
          if (!(r & jj)) {
            int r2 = r | jj;
            bool up = ((r & (k >> 6)) != 0);  // (i & k), k >= 128 here
            u64 a = v[r], c = v[r2];
            if (up ? (a > c) : (a < c)) { v[r] = c; v[r2] = a; }
          }
      } else {
#pragma unroll
        for (int r = 0; r < R; ++r) {
          u64 a = v[r];
          u64 o = __shfl_xor(a, j);
          bool up = (k >= 64) ? ((r & (k >> 6)) != 0) : ((lane & k) != 0);
          bool is_lower = ((lane & j) == 0);
          bool keep_max = up ^ is_lower;
          v[r] = keep_max ? (a > o ? a : o) : (a < o ? a : o);
        }
      }
    }
  }
#pragma unroll
  for (int r = 0; r < R; ++r) keys[r * 64 + lane] = v[r];
}

// Chunked greedy NMS over sorted (descending) keys in LDS.
// key = (score_bits<<32)|(NBOX-1-n). Appends kept (capped MAXDET). All threads enter.
__device__ void run_nms(const u64* keys, int len, const float4* __restrict__ bx,
                        float4* chbox, u64* srow, u64* keptkey, float4* keptbox,
                        u64* crossMask, int* p_kept, int tid) {
  for (int base = 0; base < len; base += 64) {
    if (*p_kept >= MAXDET) break;  // uniform (read after barrier)
    int L = min(64, len - base);
    if (tid < 64) {  // stage chunk boxes (xyxy) into LDS
      if (tid == 0) *crossMask = 0ull;
      float4 bb = make_float4(0.f, 0.f, 0.f, 0.f);
      if (tid < L) {
        u64 k = keys[base + tid];
        int orig = NBOX - 1 - (int)(k & 0xFFFFFFFFull);
        float4 c = bx[orig];
        bb = make_float4(c.x - 0.5f * c.z, c.y - 0.5f * c.w,
                         c.x + 0.5f * c.z, c.y + 0.5f * c.w);
      }
      chbox[tid] = bb;
      srow[tid] = 0ull;
    }
    __syncthreads();
    int kept0 = *p_kept;
    {  // parallel pair tests: 64 boxes x 8 slices
      int i = tid & 63, slice = tid >> 6;
      if (i < L) {
        float4 a = chbox[i];
        bool hit = false;
        for (int k0 = slice; k0 < kept0 && !hit; k0 += 8)
          if (iou_xyxy(a, keptbox[k0]) > 0.7f) hit = true;
        if (hit) atomicOr(crossMask, 1ull << i);
        u64 bits = 0ull;
        for (int j = i + 1 + slice; j < L; j += 8)
          if (iou_xyxy(a, chbox[j]) > 0.7f) bits |= 1ull << j;
        if (bits) atomicOr(&srow[i], bits);
      }
    }
    __syncthreads();
    if (tid < 64) {  // wave-parallel greedy scan
      u64 removed = *crossMask;
      if (L < 64) removed |= ~((1ull << L) - 1ull);
      u64 myrow = srow[tid];
      u64 keepm = 0ull;
      for (int ii = 0; ii < L; ++ii) {
        u64 row = __shfl(myrow, ii);
        if (!((removed >> ii) & 1ull)) {
          keepm |= 1ull << ii;
          removed |= row;
        }
      }
      if ((keepm >> tid) & 1ull) {
        int pos = kept0 + __popcll(keepm & ((1ull << tid) - 1ull));
        if (pos < MAXDET) {
          keptkey[pos] = keys[base + tid];
          keptbox[pos] = chbox[tid];
        }
      }
      if (tid == 0) *p_kept = min(MAXDET, kept0 + __popcll(keepm));
    }
    __syncthreads();
  }
}

__global__ __launch_bounds__(NT) void postproc_kernel(
    const float* __restrict__ boxes,   // [B, NBOX, 4] cxcywh
    const float* __restrict__ scores,  // [B, NBOX]
    float* __restrict__ out,           // [B*MAXDET*5] packed, then [B] num
    int B) {
  const int b = blockIdx.x;
  const int tid = threadIdx.x;
  const int wid = tid >> 6, lane = tid & 63;

  __shared__ u64 skey[NBOX];      // 32KB, fallback full sort only
  __shared__ u32 hist[8][256];    // 8KB, per-wave sub-histograms
  __shared__ u32 hmerged[256];
  __shared__ u64 cand[CAP];       // 4KB
  __shared__ float4 chbox[64];
  __shared__ u64 srow[64];
  __shared__ float4 keptbox[MAXDET];
  __shared__ u64 keptkey[MAXDET];
  __shared__ u64 crossMask;
  __shared__ int s_M, s_C, s_kept, s_ovf, s_byte, s_above, s_bcnt;

  const float* sc = scores + (size_t)b * NBOX;
  const float4* bx = (const float4*)boxes + (size_t)b * NBOX;

  if (tid == 0) { s_M = 0; s_C = 0; s_kept = 0; s_ovf = 0; }
  __syncthreads();

  // ---- Phase 1: cache score bits in regs, count valid, warm boxes into L2 ----
  u32 sb[NPT];
  int cnt = 0;
#pragma unroll
  for (int q = 0; q < NPT; ++q) {
    int n = tid + q * NT;
    float s = sc[n];
    float4 bb = bx[n];
    asm volatile("" ::"v"(bb.x), "v"(bb.z));  // keep warm-load alive
    bool valid = (s > 0.5f);
    sb[q] = valid ? __float_as_uint(s) : 0u;
    cnt += valid ? 1 : 0;
  }
#pragma unroll
  for (int d = 1; d < 64; d <<= 1) cnt += __shfl_down(cnt, d);
  if (lane == 0) atomicAdd(&s_M, cnt);
  __syncthreads();
  const int M = s_M;

  // ---- Phase 2: exact radix-select threshold (only if M > CAP) ----
  int shift = 0;
  u32 prefix = 0;
  bool ovf = false;
  if (M > CAP) {
    int needK = KSEL, aboveTot = 0, Cpred = 0;
    for (int p = 3; p >= 0; --p) {
      int sh = 8 * p;
      for (int h = tid; h < 8 * 256; h += NT) ((u32*)hist)[h] = 0u;
      __syncthreads();
#pragma unroll
      for (int q = 0; q < NPT; ++q) {
        u32 v = sb[q];
        if (v && (p == 3 || (v >> (sh + 8)) == prefix))
          atomicAdd(&hist[wid][(v >> sh) & 255u], 1u);
      }
      __syncthreads();
      if (tid < 256) {
        u32 t = 0;
#pragma unroll
        for (int w = 0; w < 8; ++w) t += hist[w][tid];
        hmerged[tid] = t;
      }
      __syncthreads();
      if (tid < 64) {  // wave 0: suffix scan over 256 bins (4/lane)
        int c0 = hmerged[tid * 4], c1 = hmerged[tid * 4 + 1];
        int c2 = hmerged[tid * 4 + 2], c3 = hmerged[tid * 4 + 3];
        int tot = c0 + c1 + c2 + c3;
        int suf = tot;
#pragma unroll
        for (int d = 1; d < 64; d <<= 1) {
          int o = __shfl_down(suf, d);
          if (tid + d < 64) suf += o;
        }
        if (suf - tot < needK && suf >= needK) {  // unique crossing lane
          int cc[4] = {c0, c1, c2, c3};
          int cum = suf - tot;
          for (int qq = 3; qq >= 0; --qq) {
            if (cum + cc[qq] >= needK) { s_byte = tid * 4 + qq; s_above = cum; s_bcnt = cc[qq]; break; }
            cum += cc[qq];
          }
        }
      }
      __syncthreads();
      prefix = (prefix << 8) | (u32)s_byte;
      aboveTot += s_above;
      needK = KSEL - aboveTot;
      Cpred = aboveTot + s_bcnt;
      shift = sh;
      if (Cpred <= CAP) break;
      __syncthreads();  // protect s_byte/s_above/s_bcnt before next pass writes
    }
    ovf = (Cpred > CAP);
  }

  // ---- Phase 3: compact candidates from registers ----
  if (!ovf) {
#pragma unroll
    for (int q = 0; q < NPT; ++q) {
      u32 v = sb[q];
      if (v && ((v >> shift) >= prefix)) {
        int pos = atomicAdd(&s_C, 1);
        if (pos < CAP)
          cand[pos] = ((u64)v << 32) | (u64)(u32)(NBOX - 1 - (tid + q * NT));
        else
          s_ovf = 1;
      }
    }
  } else if (tid == 0) {
    s_ovf = 1;
  }
  __syncthreads();
  const int C = min(s_C, CAP);
  ovf = (s_ovf != 0);

  // ---- Phase 4: barrier-free wave sort + chunked NMS ----
  if (!ovf && C > 0) {
    if (tid < 64) {
      if (C <= 256) wave_sort<4>(cand, C, lane);
      else wave_sort<8>(cand, C, lane);
    }
    __syncthreads();
    run_nms(cand, C, bx, chbox, srow, keptkey, keptbox, &crossMask, &s_kept, tid);
  }

  // ---- Phase 5: fully-general fallback (pathological inputs only) ----
  const bool need_full = ovf || (s_kept < MAXDET && C < M);
  if (need_full) {
    if (tid == 0) s_kept = 0;
#pragma unroll
    for (int q = 0; q < NPT; ++q) {
      int n = tid + q * NT;
      u64 key = (u64)(u32)(NBOX - 1 - n);
      if (sb[q]) key |= ((u64)sb[q]) << 32;
      skey[n] = key;
    }
    __syncthreads();
    for (int k = 2; k <= NBOX; k <<= 1)
      for (int j = k >> 1; j > 0; j >>= 1) {
        for (int t = tid; t < NBOX; t += NT) {
          int ixj = t ^ j;
          if (ixj > t) {
            u64 a = skey[t], c2 = skey[ixj];
            bool up = (t & k) != 0;
            if (up ? (a > c2) : (a < c2)) { skey[t] = c2; skey[ixj] = a; }
          }
        }
        __syncthreads();
      }
    run_nms(skey, M, bx, chbox, srow, keptkey, keptbox, &crossMask, &s_kept, tid);
  }

  // ---- Phase 6: outputs ----
  const int nk = s_kept;
  if (tid < MAXDET) {
    float v0 = 0.f, v1 = 0.f, v2 = 0.f, v3 = 0.f, v4 = 0.f;
    if (tid < nk) {
      u64 key = keptkey[tid];
      int orig = NBOX - 1 - (int)(key & 0xFFFFFFFFull);
      float4 bb = bx[orig];  // original cxcywh
      v0 = bb.x; v1 = bb.y; v2 = bb.z; v3 = bb.w;
      v4 = __uint_as_float((u32)(key >> 32));
    }
    float* o = out + ((size_t)b * MAXDET + tid) * 5;
    o[0] = v0; o[1] = v1; o[2] = v2; o[3] = v3; o[4] = v4;
  }
  if (tid == 0) out[(size_t)B * MAXDET * 5 + b] = (float)nk;
}

extern "C" void kernel_launch(void* const* d_in, const int* in_sizes, int n_in,
                              void* d_out, int out_size, void* d_ws, size_t ws_size,
                              hipStream_t stream) {
  const float* boxes = (const float*)d_in[0];
  const float* scores = (const float*)d_in[1];
  float* out = (float*)d_out;
  (void)d_ws; (void)ws_size; (void)n_in;
  const int B = out_size / (MAXDET * 5 + 1);  // [B,100,5] + [B]
  postproc_kernel<<<B, NT, 0, stream>>>(boxes, scores, out, B);
}

// Round 4
// 33.014 us; speedup vs baseline: 1.0548x; 1.0548x over previous
//
#include <hip/hip_runtime.h>

#define NT 1024
#define NBOX 4096
#define NPT 4        // NBOX / NT
#define NW 16        // waves per block
#define MAXDET 100
#define KSEL 192     // top-K selection target (>= 100 + NMS-suppressed margin)
#define CAP 512      // candidate capacity

typedef unsigned long long u64;
typedef unsigned int u32;

__device__ __forceinline__ float iou_xyxy(float4 a, float4 c) {
  float aa = fmaxf(a.z - a.x, 0.f) * fmaxf(a.w - a.y, 0.f);
  float ca = fmaxf(c.z - c.x, 0.f) * fmaxf(c.w - c.y, 0.f);
  float w = fmaxf(fminf(a.z, c.z) - fmaxf(a.x, c.x), 0.f);
  float h = fmaxf(fminf(a.w, c.w) - fmaxf(a.y, c.y), 0.f);
  float inter = w * h;
  return inter / fmaxf(aa + ca - inter, 1e-9f);
}

// Barrier-free descending bitonic sort of S=R*64 u64 keys by ONE wave.
template <int R>
__device__ void wave_sort(u64* keys, int C, int lane) {
  u64 v[R];
#pragma unroll
  for (int r = 0; r < R; ++r) {
    int i = r * 64 + lane;
    v[r] = (i < C) ? keys[i] : 0ull;
  }
  const int S = R * 64;
  for (int k = 2; k <= S; k <<= 1) {
    for (int j = k >> 1; j > 0; j >>= 1) {
      if (j >= 64) {
        int jj = j >> 6;
#pragma unroll
        for (int r = 0; r < R; ++r)
          if (!(r & jj)) {
            int r2 = r | jj;
            bool up = ((r & (k >> 6)) != 0);  // k >= 128 here
            u64 a = v[r], c = v[r2];
            if (up ? (a > c) : (a < c)) { v[r] = c; v[r2] = a; }
          }
      } else {
#pragma unroll
        for (int r = 0; r < R; ++r) {
          u64 a = v[r];
          u64 o = __shfl_xor(a, j);
          bool up = (k >= 64) ? ((r & (k >> 6)) != 0) : ((lane & k) != 0);
          bool is_lower = ((lane & j) == 0);
          bool keep_max = up ^ is_lower;
          v[r] = keep_max ? (a > o ? a : o) : (a < o ? a : o);
        }
      }
    }
  }
#pragma unroll
  for (int r = 0; r < R; ++r) keys[r * 64 + lane] = v[r];
}

// Chunked greedy NMS over sorted (descending) keys; boxes come from LDS sbox.
__device__ void run_nms(const u64* keys, int len, const float4* sbox,
                        float4* chbox, u64* srow, u64* keptkey, float4* keptbox,
                        u64* crossMask, int* p_kept, int tid) {
  for (int base = 0; base < len; base += 64) {
    if (*p_kept >= MAXDET) break;  // uniform (written before barrier)
    int L = min(64, len - base);
    if (tid < 64) {  // stage chunk boxes (xyxy) from LDS
      if (tid == 0) *crossMask = 0ull;
      float4 bb = make_float4(0.f, 0.f, 0.f, 0.f);
      if (tid < L) {
        u64 k = keys[base + tid];
        int orig = NBOX - 1 - (int)(k & 0xFFFFFFFFull);
        float4 c = sbox[orig];
        bb = make_float4(c.x - 0.5f * c.z, c.y - 0.5f * c.w,
                         c.x + 0.5f * c.z, c.y + 0.5f * c.w);
      }
      chbox[tid] = bb;
      srow[tid] = 0ull;
    }
    __syncthreads();
    int kept0 = *p_kept;
    {  // parallel pair tests: 64 boxes x 16 slices
      int i = tid & 63, slice = tid >> 6;
      if (i < L) {
        float4 a = chbox[i];
        bool hit = false;
        for (int k0 = slice; k0 < kept0 && !hit; k0 += NW)
          if (iou_xyxy(a, keptbox[k0]) > 0.7f) hit = true;
        if (hit) atomicOr(crossMask, 1ull << i);
        u64 bits = 0ull;
        for (int j = i + 1 + slice; j < L; j += NW)
          if (iou_xyxy(a, chbox[j]) > 0.7f) bits |= 1ull << j;
        if (bits) atomicOr(&srow[i], bits);
      }
    }
    __syncthreads();
    if (tid < 64) {  // greedy scan: sparse fast path, exact fallback
      u64 removed = *crossMask;
      if (L < 64) removed |= ~((1ull << L) - 1ull);
      u64 K = ~removed;
      u64 myrow = srow[tid];
      u64 contrib = ((K >> tid) & 1ull) ? (myrow & K) : 0ull;
#pragma unroll
      for (int d = 1; d < 64; d <<= 1) contrib |= __shfl_xor(contrib, d);
      u64 keepm;
      if (contrib == 0ull) {
        keepm = K;  // no candidate keeper suppresses another -> greedy keeps K
      } else {
        u64 removed2 = removed;
        keepm = 0ull;
        for (int ii = 0; ii < L; ++ii) {
          u64 row = __shfl(myrow, ii);
          if (!((removed2 >> ii) & 1ull)) {
            keepm |= 1ull << ii;
            removed2 |= row;
          }
        }
      }
      if ((keepm >> tid) & 1ull) {
        int pos = kept0 + __popcll(keepm & ((1ull << tid) - 1ull));
        if (pos < MAXDET) {
          keptkey[pos] = keys[base + tid];
          keptbox[pos] = chbox[tid];
        }
      }
      if (tid == 0) *p_kept = min(MAXDET, kept0 + __popcll(keepm));
    }
    __syncthreads();
  }
}

__global__ __launch_bounds__(NT) void postproc_kernel(
    const float* __restrict__ boxes,   // [B, NBOX, 4] cxcywh
    const float* __restrict__ scores,  // [B, NBOX]
    float* __restrict__ out,           // [B*MAXDET*5] packed, then [B] num
    int B) {
  const int b = blockIdx.x;
  const int tid = threadIdx.x;
  const int wid = tid >> 6, lane = tid & 63;

  __shared__ float4 sbox[NBOX];       // 64KB: all boxes staged
  __shared__ u64 skey[NBOX];          // 32KB: fallback full sort only
  __shared__ u32 hist[NW * 256];      // 16KB per-wave sub-histograms
  __shared__ u32 hmerged[256];
  __shared__ u64 cand[CAP];           // 4KB
  __shared__ float4 chbox[64];
  __shared__ u64 srow[64];
  __shared__ float4 keptbox[MAXDET];
  __shared__ u64 keptkey[MAXDET];
  __shared__ u64 crossMask;
  __shared__ int s_M, s_C, s_kept, s_ovf, s_byte, s_above, s_bcnt;

  const float* sc = scores + (size_t)b * NBOX;
  const float4* bx = (const float4*)boxes + (size_t)b * NBOX;

  if (tid == 0) { s_M = 0; s_C = 0; s_kept = 0; s_ovf = 0; }
  __syncthreads();

  // ---- Phase 1: cache score bits in regs, stage boxes to LDS, count valid ----
  u32 sb[NPT];
  int wcnt = 0;
#pragma unroll
  for (int q = 0; q < NPT; ++q) {
    int n = tid + q * NT;
    float s = sc[n];
    sbox[n] = bx[n];
    bool valid = (s > 0.5f);
    sb[q] = valid ? __float_as_uint(s) : 0u;
    u64 bal = __ballot(valid);
    if (lane == 0) wcnt += (int)__popcll(bal);
  }
  if (lane == 0) atomicAdd(&s_M, wcnt);
  __syncthreads();
  const int M = s_M;

  // ---- Phase 2: exact radix-select threshold (only if M > CAP) ----
  int shift = 0;
  u32 prefix = 0;
  bool ovf = false;
  if (M > CAP) {
    int needK = KSEL, aboveTot = 0, Cpred = 0;
    for (int p = 3; p >= 0; --p) {
      int sh = 8 * p;
      for (int h = tid; h < NW * 256; h += NT) hist[h] = 0u;
      __syncthreads();
#pragma unroll
      for (int q = 0; q < NPT; ++q) {
        u32 v = sb[q];
        bool act = v && (p == 3 || (v >> (sh + 8)) == prefix);
        u32 byte = (v >> sh) & 255u;
        u64 aball = __ballot(act);
        if (aball) {  // aball is wave-uniform
          int leader = __ffsll((unsigned long long)aball) - 1;
          u32 lb = __shfl(byte, leader);
          u64 same = __ballot(act && byte == lb);
          if (same == aball) {  // wave-uniform bin (degenerate pass): 1 atomic
            if (lane == leader) atomicAdd(&hist[wid * 256 + lb], (u32)__popcll(aball));
          } else if (act) {
            atomicAdd(&hist[wid * 256 + byte], 1u);
          }
        }
      }
      __syncthreads();
      if (tid < 256) {
        u32 t = 0;
#pragma unroll
        for (int w = 0; w < NW; ++w) t += hist[w * 256 + tid];
        hmerged[tid] = t;
      }
      __syncthreads();
      if (tid < 64) {  // wave 0: suffix scan over 256 bins (4/lane)
        int c0 = hmerged[tid * 4], c1 = hmerged[tid * 4 + 1];
        int c2 = hmerged[tid * 4 + 2], c3 = hmerged[tid * 4 + 3];
        int tot = c0 + c1 + c2 + c3;
        int suf = tot;
#pragma unroll
        for (int d = 1; d < 64; d <<= 1) {
          int o = __shfl_down(suf, d);
          if (tid + d < 64) suf += o;
        }
        if (suf - tot < needK && suf >= needK) {  // unique crossing lane
          int cc[4] = {c0, c1, c2, c3};
          int cum = suf - tot;
          for (int qq = 3; qq >= 0; --qq) {
            if (cum + cc[qq] >= needK) { s_byte = tid * 4 + qq; s_above = cum; s_bcnt = cc[qq]; break; }
            cum += cc[qq];
          }
        }
      }
      __syncthreads();
      prefix = (prefix << 8) | (u32)s_byte;
      aboveTot += s_above;
      needK = KSEL - aboveTot;
      Cpred = aboveTot + s_bcnt;
      shift = sh;
      if (Cpred <= CAP) break;
      __syncthreads();  // protect s_* before next pass overwrites
    }
    ovf = (Cpred > CAP);
  }

  // ---- Phase 3: compact candidates (wave-aggregated atomics) ----
  if (!ovf) {
#pragma unroll
    for (int q = 0; q < NPT; ++q) {
      u32 v = sb[q];
      bool take = v && ((v >> shift) >= prefix);
      u64 bal = __ballot(take);
      if (bal) {  // wave-uniform
        int leader = __ffsll((unsigned long long)bal) - 1;
        int basep = 0;
        if (lane == leader) basep = atomicAdd(&s_C, (int)__popcll(bal));
        basep = __shfl(basep, leader);
        if (take) {
          int pos = basep + (int)__popcll(bal & ((1ull << lane) - 1ull));
          if (pos < CAP)
            cand[pos] = ((u64)v << 32) | (u64)(u32)(NBOX - 1 - (tid + q * NT));
          else
            s_ovf = 1;
        }
      }
    }
  } else if (tid == 0) {
    s_ovf = 1;
  }
  __syncthreads();
  const int C = min(s_C, CAP);
  ovf = (s_ovf != 0);

  // ---- Phase 4: barrier-free wave sort + chunked NMS ----
  if (!ovf && C > 0) {
    if (tid < 64) {
      if (C <= 256) wave_sort<4>(cand, C, lane);
      else wave_sort<8>(cand, C, lane);
    }
    __syncthreads();
    run_nms(cand, C, sbox, chbox, srow, keptkey, keptbox, &crossMask, &s_kept, tid);
  }

  // ---- Phase 5: fully-general fallback (pathological inputs only) ----
  const bool need_full = ovf || (s_kept < MAXDET && C < M);
  if (need_full) {
    if (tid == 0) s_kept = 0;
#pragma unroll
    for (int q = 0; q < NPT; ++q) {
      int n = tid + q * NT;
      u64 key = (u64)(u32)(NBOX - 1 - n);
      if (sb[q]) key |= ((u64)sb[q]) << 32;
      skey[n] = key;
    }
    __syncthreads();
    for (int k = 2; k <= NBOX; k <<= 1)
      for (int j = k >> 1; j > 0; j >>= 1) {
        for (int t = tid; t < NBOX; t += NT) {
          int ixj = t ^ j;
          if (ixj > t) {
            u64 a = skey[t], c2 = skey[ixj];
            bool up = (t & k) != 0;
            if (up ? (a > c2) : (a < c2)) { skey[t] = c2; skey[ixj] = a; }
          }
        }
        __syncthreads();
      }
    run_nms(skey, M, sbox, chbox, srow, keptkey, keptbox, &crossMask, &s_kept, tid);
  }

  // ---- Phase 6: outputs ----
  const int nk = s_kept;
  if (tid < MAXDET) {
    float v0 = 0.f, v1 = 0.f, v2 = 0.f, v3 = 0.f, v4 = 0.f;
    if (tid < nk) {
      u64 key = keptkey[tid];
      int orig = NBOX - 1 - (int)(key & 0xFFFFFFFFull);
      float4 bb = sbox[orig];  // original cxcywh
      v0 = bb.x; v1 = bb.y; v2 = bb.z; v3 = bb.w;
      v4 = __uint_as_float((u32)(key >> 32));
    }
    float* o = out + ((size_t)b * MAXDET + tid) * 5;
    o[0] = v0; o[1] = v1; o[2] = v2; o[3] = v3; o[4] = v4;
  }
  if (tid == 0) out[(size_t)B * MAXDET * 5 + b] = (float)nk;
}

extern "C" void kernel_launch(void* const* d_in, const int* in_sizes, int n_in,
                              void* d_out, int out_size, void* d_ws, size_t ws_size,
                              hipStream_t stream) {
  const float* boxes = (const float*)d_in[0];
  const float* scores = (const float*)d_in[1];
  float* out = (float*)d_out;
  (void)d_ws; (void)ws_size; (void)n_in;
  const int B = out_size / (MAXDET * 5 + 1);  // [B,100,5] + [B]
  postproc_kernel<<<B, NT, 0, stream>>>(boxes, scores, out, B);
}